// Round 7
// baseline (139.148 us; speedup 1.0000x reference)
//
#include <hip/hip_runtime.h>

// T=4096, B=8, E=512. Dual EMA (pos/neg split) along T. fp32 in/out.
//   pb = sigmoid(raw_pos_beta[e]); nb = sigmoid(raw_neg_beta[e])
//   mem_p[t] = pb*mem_p[t-1] + max(x,0)*(1-pb)
//   mem_n[t] = nb*mem_n[t-1] + min(x,0)*(1-nb)
//   out[t,b,e] = mem_p + mem_n
//
// TWO dispatches, ZERO inter-block sync, EXACT carries (r6's redundant
// fold cost ~260MB of serialized L2 reads ~7.5us/CU; replaced by an
// in-block scan):
//   k_carr: 256 blocks x 512 threads. Block owns a 16-col stripe x ALL 128
//           chunks. Phase 1: per-thread (chunk c, quad qg) chunk aggregates
//           (zero-init local scan, 32 strided float4 loads; 64B wave
//           segments — over-fetch recycled by k_main's LLC re-read).
//           Phase 2: in-block affine scan over chunks: fold-8 per thread,
//           4-round Hillis-Steele over 16 chunk-groups in LDS ((A,B)
//           composition, A=beta^32), then write exact EXCLUSIVE carries
//           carr[(c*2+s)*BE + col] (4 MB ws, fully overwritten -> poison-
//           safe, no flags).
//   k_main: r6's kernel minus the fold: read 2 float4 carries, seed, stream
//           32 t-steps x->out (perfect 1KB/wave coalescing, x LLC-resident).
// History: r0 trio 135.9 | r1 coop 417 | r5 flag-pipeline 517 | r6
// redundant-fold 129.7. Device-scope spin/fence sync is catastrophic on
// CDNA4; stream-ordered dispatch is the only cheap cross-block dependency.
// dur_us carries ~86us of unavoidable harness poison-fills.
// Fallback: verified r0 trio if ws < 4 MB.

#define T_DIM 4096
#define B_DIM 8
#define E_DIM 512
#define CHUNK_L 32
#define NCHUNK (T_DIM / CHUNK_L)   // 128
#define BE (B_DIM * E_DIM)         // 4096

__device__ __forceinline__ float sigmoidf_(float x) { return 1.0f / (1.0f + __expf(-x)); }
__device__ __forceinline__ float pow32_(float b) { float t = b * b; t *= t; t *= t; t *= t; t *= t; return t; }

// ---- k_carr: exact exclusive carries via in-block scan ----
__global__ __launch_bounds__(512) void k_carr(
        const float* __restrict__ x,
        const float* __restrict__ rp,
        const float* __restrict__ rn,
        float* __restrict__ carr) {
    __shared__ float Fs[NCHUNK * 33];      // [128 chunks][32 sc] padded +1
    __shared__ float sA[16 * 32];          // [16 cg][32 sc]
    __shared__ float sB[16 * 32];

    const int e0g = blockIdx.x * 16;       // global col base (16-col stripe)
    const int tid = threadIdx.x;           // 0..511

    // ---- phase 1: chunk aggregates (zero-init local scans)
    {
        const int c   = tid >> 2;          // chunk 0..127
        const int qg  = tid & 3;           // quad 0..3
        const int cg0 = e0g + qg * 4;      // global col of this quad
        const int eb  = cg0 & 511;         // e index for betas
        float4 rp4 = *(const float4*)(rp + eb);
        float4 rn4 = *(const float4*)(rn + eb);
        float bp[4] = {sigmoidf_(rp4.x), sigmoidf_(rp4.y), sigmoidf_(rp4.z), sigmoidf_(rp4.w)};
        float bn[4] = {sigmoidf_(rn4.x), sigmoidf_(rn4.y), sigmoidf_(rn4.z), sigmoidf_(rn4.w)};
        float fp[4] = {0.f, 0.f, 0.f, 0.f};
        float fn[4] = {0.f, 0.f, 0.f, 0.f};
        const size_t xb = (size_t)c * CHUNK_L * BE + cg0;
        #pragma unroll
        for (int k = 0; k < CHUNK_L; k++) {
            float4 xv = *(const float4*)(x + xb + (size_t)k * BE);
            float f[4] = {xv.x, xv.y, xv.z, xv.w};
            #pragma unroll
            for (int j = 0; j < 4; j++) {
                fp[j] = bp[j] * fp[j] + fmaxf(f[j], 0.f) * (1.0f - bp[j]);
                fn[j] = bn[j] * fn[j] + fminf(f[j], 0.f) * (1.0f - bn[j]);
            }
        }
        const int sc0 = qg * 4;
        #pragma unroll
        for (int j = 0; j < 4; j++) {
            Fs[c * 33 + sc0 + j]      = fp[j];   // sc 0..15 = pos
            Fs[c * 33 + 16 + sc0 + j] = fn[j];   // sc 16..31 = neg
        }
    }
    __syncthreads();

    // ---- phase 2: affine scan over chunks; write exclusive carries
    const int sc   = tid & 31;             // scan-column 0..31
    const int cg   = tid >> 5;             // chunk-group 0..15 (8 chunks each)
    const int colg = e0g + (sc & 15);      // global col
    const int s    = sc >> 4;              // 0 = pos, 1 = neg
    const float beta = sigmoidf_((s ? rn : rp)[colg & 511]);
    const float A = pow32_(beta);          // beta^32 per chunk

    // fold 8 chunks (ascending) -> (A8, B8)
    float B8 = 0.f;
    #pragma unroll
    for (int u = 0; u < 8; u++) B8 = A * B8 + Fs[(cg * 8 + u) * 33 + sc];
    float A8; { float t = A * A; t *= t; A8 = t * t; }   // A^8

    // Hillis-Steele inclusive scan over the 16 chunk-groups
    float curA = A8, curB = B8;
    #pragma unroll
    for (int d = 1; d < 16; d <<= 1) {
        sA[cg * 32 + sc] = curA;
        sB[cg * 32 + sc] = curB;
        __syncthreads();
        if (cg >= d) {
            float pA = sA[(cg - d) * 32 + sc];
            float pB = sB[(cg - d) * 32 + sc];
            curB = curA * pB + curB;       // compose: prev then cur
            curA = curA * pA;
        }
        __syncthreads();
    }
    sB[cg * 32 + sc] = curB;               // inclusive B per (cg, sc)
    __syncthreads();
    float E = (cg == 0) ? 0.f : sB[(cg - 1) * 32 + sc];  // carry into chunk cg*8

    #pragma unroll
    for (int u = 0; u < 8; u++) {
        const int c = cg * 8 + u;
        carr[(size_t)(c * 2 + s) * BE + colg] = E;       // carry INTO chunk c
        E = A * E + Fs[c * 33 + sc];
    }
}

// ---- k_main: seed from exact carries, stream chunk (r6 minus fold) ----
__global__ __launch_bounds__(256) void ParallelDLIEMA_17789754541002_kernel(
        const float* __restrict__ x,
        const float* __restrict__ rp,
        const float* __restrict__ rn,
        const float* __restrict__ carr,
        float* __restrict__ out) {
    const int gtid = blockIdx.x * 256 + threadIdx.x;
    const int q = gtid & 1023;             // col-quad 0..1023
    const int c = gtid >> 10;              // chunk 0..127
    const int e = (q & 127) * 4;
    const int b = q >> 7;
    const int col = b * E_DIM + e;

    float4 rp4 = *(const float4*)(rp + e);
    float4 rn4 = *(const float4*)(rn + e);
    float bp[4] = {sigmoidf_(rp4.x), sigmoidf_(rp4.y), sigmoidf_(rp4.z), sigmoidf_(rp4.w)};
    float bn[4] = {sigmoidf_(rn4.x), sigmoidf_(rn4.y), sigmoidf_(rn4.z), sigmoidf_(rn4.w)};

    float4 cp = *(const float4*)(carr + (size_t)(c * 2 + 0) * BE + col);
    float4 cn = *(const float4*)(carr + (size_t)(c * 2 + 1) * BE + col);
    float sp[4] = {cp.x, cp.y, cp.z, cp.w};
    float sn[4] = {cn.x, cn.y, cn.z, cn.w};

    const size_t xbase = (size_t)c * CHUNK_L * BE + col;
    #pragma unroll
    for (int k = 0; k < CHUNK_L; k++) {
        float4 xv = *(const float4*)(x + xbase + (size_t)k * BE);
        float f[4] = {xv.x, xv.y, xv.z, xv.w};
        float o[4];
        #pragma unroll
        for (int j = 0; j < 4; j++) {
            sp[j] = bp[j] * sp[j] + fmaxf(f[j], 0.f) * (1.0f - bp[j]);
            sn[j] = bn[j] * sn[j] + fminf(f[j], 0.f) * (1.0f - bn[j]);
            o[j] = sp[j] + sn[j];
        }
        *(float4*)(out + xbase + (size_t)k * BE) = make_float4(o[0], o[1], o[2], o[3]);
    }
}

// ================= fallback: verified round-0 3-kernel path (135.9us) ====

#define FB_CHUNK_L 16
#define FB_NCHUNK (T_DIM / FB_CHUNK_L)   // 256

__global__ __launch_bounds__(256) void k1_local(
        const float* __restrict__ x, const float* __restrict__ rp,
        const float* __restrict__ rn, float* __restrict__ out) {
    int gtid = blockIdx.x * 256 + threadIdx.x;
    int e4 = gtid & 127; int b = (gtid >> 7) & 7; int c = gtid >> 10; int e = e4 * 4;
    float4 rp4 = *(const float4*)(rp + e);
    float4 rn4 = *(const float4*)(rn + e);
    float bp[4] = {sigmoidf_(rp4.x), sigmoidf_(rp4.y), sigmoidf_(rp4.z), sigmoidf_(rp4.w)};
    float bn[4] = {sigmoidf_(rn4.x), sigmoidf_(rn4.y), sigmoidf_(rn4.z), sigmoidf_(rn4.w)};
    float fp4[4] = {0.f,0.f,0.f,0.f}, fn4[4] = {0.f,0.f,0.f,0.f};
    int base = c * FB_CHUNK_L * BE + b * E_DIM + e;
    #pragma unroll
    for (int k = 0; k < FB_CHUNK_L; k++) {
        float4 xv = *(const float4*)(x + base + k * BE);
        float f[4] = {xv.x, xv.y, xv.z, xv.w};
        #pragma unroll
        for (int j = 0; j < 4; j++) {
            fp4[j] = bp[j] * fp4[j] + fmaxf(f[j], 0.f) * (1.0f - bp[j]);
            fn4[j] = bn[j] * fn4[j] + fminf(f[j], 0.f) * (1.0f - bn[j]);
        }
    }
    *(float4*)(out + base + 0 * BE) = make_float4(fp4[0], fp4[1], fp4[2], fp4[3]);
    *(float4*)(out + base + 1 * BE) = make_float4(fn4[0], fn4[1], fn4[2], fn4[3]);
}

__global__ __launch_bounds__(256) void k_carry(const float* __restrict__ rp,
                                               const float* __restrict__ rn,
                                               float* __restrict__ out) {
    int gtid = blockIdx.x * 256 + threadIdx.x;
    int e = gtid & 511; int b = (gtid >> 9) & 7; int s = gtid >> 12;
    float beta = sigmoidf_(s ? rn[e] : rp[e]);
    float bl = beta * beta; bl = bl * bl; bl = bl * bl; bl = bl * bl;
    float* p = out + s * BE + b * E_DIM + e;
    float carry = 0.f;
    for (int g = 0; g < FB_NCHUNK / 16; g++) {
        float fv[16];
        #pragma unroll
        for (int u = 0; u < 16; u++) fv[u] = p[(g * 16 + u) * (FB_CHUNK_L * BE)];
        #pragma unroll
        for (int u = 0; u < 16; u++) {
            p[(g * 16 + u) * (FB_CHUNK_L * BE)] = carry;
            carry = bl * carry + fv[u];
        }
    }
}

__global__ __launch_bounds__(256) void k_out(const float* __restrict__ x,
                                             const float* __restrict__ rp,
                                             const float* __restrict__ rn,
                                             float* __restrict__ out) {
    int gtid = blockIdx.x * 256 + threadIdx.x;
    int e4 = gtid & 127; int b = (gtid >> 7) & 7; int c = gtid >> 10; int e = e4 * 4;
    float4 rp4 = *(const float4*)(rp + e);
    float4 rn4 = *(const float4*)(rn + e);
    float bp[4] = {sigmoidf_(rp4.x), sigmoidf_(rp4.y), sigmoidf_(rp4.z), sigmoidf_(rp4.w)};
    float bn[4] = {sigmoidf_(rn4.x), sigmoidf_(rn4.y), sigmoidf_(rn4.z), sigmoidf_(rn4.w)};
    int base = c * FB_CHUNK_L * BE + b * E_DIM + e;
    float4 cp = *(const float4*)(out + base + 0 * BE);
    float4 cn = *(const float4*)(out + base + 1 * BE);
    float lp[4] = {cp.x, cp.y, cp.z, cp.w};
    float ln[4] = {cn.x, cn.y, cn.z, cn.w};
    #pragma unroll
    for (int k = 0; k < FB_CHUNK_L; k++) {
        float4 xv = *(const float4*)(x + base + k * BE);
        float f[4] = {xv.x, xv.y, xv.z, xv.w};
        float o[4];
        #pragma unroll
        for (int j = 0; j < 4; j++) {
            lp[j] = bp[j] * lp[j] + fmaxf(f[j], 0.f) * (1.0f - bp[j]);
            ln[j] = bn[j] * ln[j] + fminf(f[j], 0.f) * (1.0f - bn[j]);
            o[j] = lp[j] + ln[j];
        }
        *(float4*)(out + base + k * BE) = make_float4(o[0], o[1], o[2], o[3]);
    }
}

extern "C" void kernel_launch(void* const* d_in, const int* in_sizes, int n_in,
                              void* d_out, int out_size, void* d_ws, size_t ws_size,
                              hipStream_t stream) {
    const float* x  = (const float*)d_in[0];
    const float* rp = (const float*)d_in[1];
    const float* rn = (const float*)d_in[2];
    float* out = (float*)d_out;

    const size_t need = (size_t)2 * NCHUNK * BE * sizeof(float);   // 4 MB carr
    if (d_ws != nullptr && ws_size >= need) {
        float* carr = (float*)d_ws;
        // k_carr: 4096 cols / 16-col stripes = 256 blocks
        k_carr<<<256, 512, 0, stream>>>(x, rp, rn, carr);
        // k_main: 128 chunks * 1024 col-quads = 512 blocks
        ParallelDLIEMA_17789754541002_kernel<<<512, 256, 0, stream>>>(x, rp, rn, carr, out);
    } else {
        // verified fallback (135.9 us)
        k1_local<<<1024, 256, 0, stream>>>(x, rp, rn, out);
        k_carry<<<32, 256, 0, stream>>>(rp, rn, out);
        k_out<<<1024, 256, 0, stream>>>(x, rp, rn, out);
    }
}

// Round 8
// 132.365 us; speedup vs baseline: 1.0512x; 1.0512x over previous
//
#include <hip/hip_runtime.h>

// T=4096, B=8, E=512. Dual EMA (pos/neg split) along T. fp32 in/out.
//   pb = sigmoid(raw_pos_beta[e]); nb = sigmoid(raw_neg_beta[e])
//   mem_p[t] = pb*mem_p[t-1] + max(x,0)*(1-pb)
//   mem_n[t] = nb*mem_n[t-1] + min(x,0)*(1-nb)
//   out[t,b,e] = mem_p + mem_n
//
// TWO dispatches, ZERO inter-block sync. r6 structure (129.7us champion)
// with CHUNK_L 32->64: the redundant-fold L2 traffic scales as NCHUNK^2
// (1024*32*NCHUNK^2/2 bytes = 268MB @128 -> 67MB @64), while both kernels
// keep the perfectly-coalesced 1KB/wave x pattern (r7's 16-col-stripe
// k_carr broke coalescing and regressed to 139us -> reverted).
//   k_agg : thread (c,q) scans its chunk (64 t-steps, zero init), writes
//           chunk aggregate to ws (2 MB, fully overwritten -> poison-safe).
//   k_main: thread (c,q) REDUNDANTLY folds carry over agg[0..c-1]
//           (A = beta^64 composition, L2-resident), then streams its chunk
//           x -> out seeded with the carry (x LLC-resident from k_agg).
// History: r0 trio 135.9 | r1 coop 417 | r5 flag-pipeline 517 | r6
// fold@128 129.7 | r7 stripe-carr 139.1. Device-scope spin/fence sync is
// catastrophic on CDNA4; stream-ordered dispatch is the only cheap
// cross-block dependency. dur_us carries ~86us of harness poison-fills.
// Fallback: verified r0 trio if ws < 2 MB.

#define T_DIM 4096
#define B_DIM 8
#define E_DIM 512
#define CHUNK_L 64
#define NCHUNK (T_DIM / CHUNK_L)   // 64
#define BE (B_DIM * E_DIM)         // 4096

__device__ __forceinline__ float sigmoidf_(float x) { return 1.0f / (1.0f + __expf(-x)); }
// beta^64 = six squarings
__device__ __forceinline__ float pow64_(float b) {
    float t = b * b; t *= t; t *= t; t *= t; t *= t; t *= t; return t;
}

// k_agg: 65536 threads; thread = (c, q). 64 strided float4 loads of x.
__global__ __launch_bounds__(256) void k_agg(
        const float* __restrict__ x,
        const float* __restrict__ rp,
        const float* __restrict__ rn,
        float* __restrict__ agg) {
    const int gtid = blockIdx.x * 256 + threadIdx.x;
    const int q = gtid & 1023;          // col-quad 0..1023
    const int c = gtid >> 10;           // chunk 0..63
    const int e = (q & 127) * 4;
    const int b = q >> 7;
    const int col = b * E_DIM + e;

    float4 rp4 = *(const float4*)(rp + e);
    float4 rn4 = *(const float4*)(rn + e);
    float bp[4] = {sigmoidf_(rp4.x), sigmoidf_(rp4.y), sigmoidf_(rp4.z), sigmoidf_(rp4.w)};
    float bn[4] = {sigmoidf_(rn4.x), sigmoidf_(rn4.y), sigmoidf_(rn4.z), sigmoidf_(rn4.w)};

    float fp[4] = {0.f, 0.f, 0.f, 0.f};
    float fn[4] = {0.f, 0.f, 0.f, 0.f};
    const size_t xbase = (size_t)c * CHUNK_L * BE + col;
    #pragma unroll 8
    for (int k = 0; k < CHUNK_L; k++) {
        float4 xv = *(const float4*)(x + xbase + (size_t)k * BE);
        float f[4] = {xv.x, xv.y, xv.z, xv.w};
        #pragma unroll
        for (int j = 0; j < 4; j++) {
            fp[j] = bp[j] * fp[j] + fmaxf(f[j], 0.f) * (1.0f - bp[j]);
            fn[j] = bn[j] * fn[j] + fminf(f[j], 0.f) * (1.0f - bn[j]);
        }
    }
    *(float4*)(agg + (size_t)(c * 2 + 0) * BE + col) = make_float4(fp[0], fp[1], fp[2], fp[3]);
    *(float4*)(agg + (size_t)(c * 2 + 1) * BE + col) = make_float4(fn[0], fn[1], fn[2], fn[3]);
}

// k_main: redundant prefix fold (L2-resident agg), then stream chunk.
__global__ __launch_bounds__(256) void ParallelDLIEMA_17789754541002_kernel(
        const float* __restrict__ x,
        const float* __restrict__ rp,
        const float* __restrict__ rn,
        const float* __restrict__ agg,
        float* __restrict__ out) {
    const int gtid = blockIdx.x * 256 + threadIdx.x;
    const int q = gtid & 1023;
    const int c = gtid >> 10;
    const int e = (q & 127) * 4;
    const int b = q >> 7;
    const int col = b * E_DIM + e;

    float4 rp4 = *(const float4*)(rp + e);
    float4 rn4 = *(const float4*)(rn + e);
    float bp[4] = {sigmoidf_(rp4.x), sigmoidf_(rp4.y), sigmoidf_(rp4.z), sigmoidf_(rp4.w)};
    float bn[4] = {sigmoidf_(rn4.x), sigmoidf_(rn4.y), sigmoidf_(rn4.z), sigmoidf_(rn4.w)};

    float Ap[4], An[4];                 // beta^64
    #pragma unroll
    for (int j = 0; j < 4; j++) { Ap[j] = pow64_(bp[j]); An[j] = pow64_(bn[j]); }

    // redundant fold: carry into chunk c (ascending j; s = A*s + F_j)
    float sp[4] = {0.f, 0.f, 0.f, 0.f};
    float sn[4] = {0.f, 0.f, 0.f, 0.f};
    #pragma unroll 4
    for (int j = 0; j < c; ++j) {
        float4 ap = *(const float4*)(agg + (size_t)(j * 2 + 0) * BE + col);
        float4 an = *(const float4*)(agg + (size_t)(j * 2 + 1) * BE + col);
        sp[0] = Ap[0] * sp[0] + ap.x;  sn[0] = An[0] * sn[0] + an.x;
        sp[1] = Ap[1] * sp[1] + ap.y;  sn[1] = An[1] * sn[1] + an.y;
        sp[2] = Ap[2] * sp[2] + ap.z;  sn[2] = An[2] * sn[2] + an.z;
        sp[3] = Ap[3] * sp[3] + ap.w;  sn[3] = An[3] * sn[3] + an.w;
    }

    // stream chunk: x (LLC-resident) -> out, seeded with the carry
    const size_t xbase = (size_t)c * CHUNK_L * BE + col;
    #pragma unroll 8
    for (int k = 0; k < CHUNK_L; k++) {
        float4 xv = *(const float4*)(x + xbase + (size_t)k * BE);
        float f[4] = {xv.x, xv.y, xv.z, xv.w};
        float o[4];
        #pragma unroll
        for (int j = 0; j < 4; j++) {
            sp[j] = bp[j] * sp[j] + fmaxf(f[j], 0.f) * (1.0f - bp[j]);
            sn[j] = bn[j] * sn[j] + fminf(f[j], 0.f) * (1.0f - bn[j]);
            o[j] = sp[j] + sn[j];
        }
        *(float4*)(out + xbase + (size_t)k * BE) = make_float4(o[0], o[1], o[2], o[3]);
    }
}

// ================= fallback: verified round-0 3-kernel path (135.9us) ====

#define FB_CHUNK_L 16
#define FB_NCHUNK (T_DIM / FB_CHUNK_L)   // 256

__global__ __launch_bounds__(256) void k1_local(
        const float* __restrict__ x, const float* __restrict__ rp,
        const float* __restrict__ rn, float* __restrict__ out) {
    int gtid = blockIdx.x * 256 + threadIdx.x;
    int e4 = gtid & 127; int b = (gtid >> 7) & 7; int c = gtid >> 10; int e = e4 * 4;
    float4 rp4 = *(const float4*)(rp + e);
    float4 rn4 = *(const float4*)(rn + e);
    float bp[4] = {sigmoidf_(rp4.x), sigmoidf_(rp4.y), sigmoidf_(rp4.z), sigmoidf_(rp4.w)};
    float bn[4] = {sigmoidf_(rn4.x), sigmoidf_(rn4.y), sigmoidf_(rn4.z), sigmoidf_(rn4.w)};
    float fp4[4] = {0.f,0.f,0.f,0.f}, fn4[4] = {0.f,0.f,0.f,0.f};
    int base = c * FB_CHUNK_L * BE + b * E_DIM + e;
    #pragma unroll
    for (int k = 0; k < FB_CHUNK_L; k++) {
        float4 xv = *(const float4*)(x + base + k * BE);
        float f[4] = {xv.x, xv.y, xv.z, xv.w};
        #pragma unroll
        for (int j = 0; j < 4; j++) {
            fp4[j] = bp[j] * fp4[j] + fmaxf(f[j], 0.f) * (1.0f - bp[j]);
            fn4[j] = bn[j] * fn4[j] + fminf(f[j], 0.f) * (1.0f - bn[j]);
        }
    }
    *(float4*)(out + base + 0 * BE) = make_float4(fp4[0], fp4[1], fp4[2], fp4[3]);
    *(float4*)(out + base + 1 * BE) = make_float4(fn4[0], fn4[1], fn4[2], fn4[3]);
}

__global__ __launch_bounds__(256) void k_carry(const float* __restrict__ rp,
                                               const float* __restrict__ rn,
                                               float* __restrict__ out) {
    int gtid = blockIdx.x * 256 + threadIdx.x;
    int e = gtid & 511; int b = (gtid >> 9) & 7; int s = gtid >> 12;
    float beta = sigmoidf_(s ? rn[e] : rp[e]);
    float bl = beta * beta; bl = bl * bl; bl = bl * bl; bl = bl * bl;
    float* p = out + s * BE + b * E_DIM + e;
    float carry = 0.f;
    for (int g = 0; g < FB_NCHUNK / 16; g++) {
        float fv[16];
        #pragma unroll
        for (int u = 0; u < 16; u++) fv[u] = p[(g * 16 + u) * (FB_CHUNK_L * BE)];
        #pragma unroll
        for (int u = 0; u < 16; u++) {
            p[(g * 16 + u) * (FB_CHUNK_L * BE)] = carry;
            carry = bl * carry + fv[u];
        }
    }
}

__global__ __launch_bounds__(256) void k_out(const float* __restrict__ x,
                                             const float* __restrict__ rp,
                                             const float* __restrict__ rn,
                                             float* __restrict__ out) {
    int gtid = blockIdx.x * 256 + threadIdx.x;
    int e4 = gtid & 127; int b = (gtid >> 7) & 7; int c = gtid >> 10; int e = e4 * 4;
    float4 rp4 = *(const float4*)(rp + e);
    float4 rn4 = *(const float4*)(rn + e);
    float bp[4] = {sigmoidf_(rp4.x), sigmoidf_(rp4.y), sigmoidf_(rp4.z), sigmoidf_(rp4.w)};
    float bn[4] = {sigmoidf_(rn4.x), sigmoidf_(rn4.y), sigmoidf_(rn4.z), sigmoidf_(rn4.w)};
    int base = c * FB_CHUNK_L * BE + b * E_DIM + e;
    float4 cp = *(const float4*)(out + base + 0 * BE);
    float4 cn = *(const float4*)(out + base + 1 * BE);
    float lp[4] = {cp.x, cp.y, cp.z, cp.w};
    float ln[4] = {cn.x, cn.y, cn.z, cn.w};
    #pragma unroll
    for (int k = 0; k < FB_CHUNK_L; k++) {
        float4 xv = *(const float4*)(x + base + k * BE);
        float f[4] = {xv.x, xv.y, xv.z, xv.w};
        float o[4];
        #pragma unroll
        for (int j = 0; j < 4; j++) {
            lp[j] = bp[j] * lp[j] + fmaxf(f[j], 0.f) * (1.0f - bp[j]);
            ln[j] = bn[j] * ln[j] + fminf(f[j], 0.f) * (1.0f - bn[j]);
            o[j] = lp[j] + ln[j];
        }
        *(float4*)(out + base + k * BE) = make_float4(o[0], o[1], o[2], o[3]);
    }
}

extern "C" void kernel_launch(void* const* d_in, const int* in_sizes, int n_in,
                              void* d_out, int out_size, void* d_ws, size_t ws_size,
                              hipStream_t stream) {
    const float* x  = (const float*)d_in[0];
    const float* rp = (const float*)d_in[1];
    const float* rn = (const float*)d_in[2];
    float* out = (float*)d_out;

    const size_t need = (size_t)2 * NCHUNK * BE * sizeof(float);   // 2 MB
    if (d_ws != nullptr && ws_size >= need) {
        float* agg = (float*)d_ws;
        // 64 chunks * 1024 col-quads = 65536 threads = 256 blocks
        k_agg<<<256, 256, 0, stream>>>(x, rp, rn, agg);
        ParallelDLIEMA_17789754541002_kernel<<<256, 256, 0, stream>>>(x, rp, rn, agg, out);
    } else {
        // verified fallback (135.9 us)
        k1_local<<<1024, 256, 0, stream>>>(x, rp, rn, out);
        k_carry<<<32, 256, 0, stream>>>(rp, rn, out);
        k_out<<<1024, 256, 0, stream>>>(x, rp, rn, out);
    }
}